// Round 10
// baseline (607.570 us; speedup 1.0000x reference)
//
#include <hip/hip_runtime.h>
#include <hip/hip_cooperative_groups.h>

namespace cg = cooperative_groups;

#define N_USER   300000
#define M_ITEM   700000
#define N_NODES  (N_USER + M_ITEM)
#define DIM      64
#define N_EDGES  1200000
#define BATCH    4096

#define POOLROWS 131072          // pooled rows, need ~59K
#define CAPE     131072          // edge entries per class segment, need ~40K max
#define SCHUNK   4096
#define NBLK_M   ((N_NODES + SCHUNK - 1) / SCHUNK)   // 245 map chunks
#define NBLK_E   ((N_EDGES + SCHUNK - 1) / SCHUNK)   // 293 edge chunks

#define GRID 512
#define TPB  256

// counters (64B-padded)
#define C_ROW 0
#define C_N3  16
#define C_N2  32
#define C_N1  48

// map encoding: 0 = unmarked; 1..3 = raw mark level m; (m<<24)|base = assigned.
__device__ __forceinline__ int level_of(int x) {
    return (x >= (1 << 24)) ? (x >> 24) : x;
}

// ---------------------------------------------------------------------------
// Threefry2x32-20, JAX partitionable path (bit-exact, verified round 2).
// ---------------------------------------------------------------------------
__device__ __forceinline__ unsigned rotl32(unsigned x, int r) {
    return (x << r) | (x >> (32 - r));
}

__device__ __forceinline__ float edge_veff(int e, const float* __restrict__ evals) {
    unsigned ks[3] = {0u, 42u, 0u ^ 42u ^ 0x1BD11BDAu};
    unsigned x0 = ks[0];
    unsigned x1 = (unsigned)e + ks[1];
    const int rotA[4] = {13, 15, 26, 6};
    const int rotB[4] = {17, 29, 16, 24};
#pragma unroll
    for (int g = 0; g < 5; ++g) {
#pragma unroll
        for (int j = 0; j < 4; ++j) {
            int r = (g & 1) ? rotB[j] : rotA[j];
            x0 += x1;
            x1 = rotl32(x1, r);
            x1 ^= x0;
        }
        x0 += ks[(g + 1) % 3];
        x1 += ks[(g + 2) % 3] + (unsigned)(g + 1);
    }
    unsigned bits = x0 ^ x1;
    float u = __uint_as_float((bits >> 9) | 0x3F800000u) - 1.0f;
    return (u >= 0.1f) ? evals[e] * (1.0f / 0.9f) : 0.0f;
}

// ---------------------------------------------------------------------------
// The whole pipeline in one cooperative kernel. Phases separated by
// grid.sync() (replaces 8 kernel-boundary drains at ~15us each).
// ---------------------------------------------------------------------------
__global__ __launch_bounds__(TPB) void mega_kernel(
    const float* __restrict__ user_emb, const float* __restrict__ item_emb,
    const float* __restrict__ evals,
    const int* __restrict__ esrc, const int* __restrict__ edst,
    const int* __restrict__ users, const int* __restrict__ items,
    int* __restrict__ map, float* __restrict__ pool, int* __restrict__ cnt,
    int* __restrict__ el_src, int* __restrict__ el_dst, float* __restrict__ el_v,
    float* __restrict__ ratings, float* __restrict__ inter,
    float* __restrict__ inter_layers)
{
    cg::grid_group grid = cg::this_grid();
    const int tid  = blockIdx.x * TPB + threadIdx.x;
    const int nthr = GRID * TPB;  // 131072

    // ---- P0: zero map (int4) + counters ----
    {
        int4* map4 = (int4*)map;
        int4 z = make_int4(0, 0, 0, 0);
        for (int i = tid; i < N_NODES / 4; i += nthr) map4[i] = z;
        if (tid < 64) cnt[tid] = 0;
    }
    grid.sync();

    // ---- P1: seed sampled nodes with m=3 (idempotent stores) ----
    for (int t = tid; t < 2 * BATCH; t += nthr) {
        int node = (t < BATCH) ? users[t] : (N_USER + items[t - BATCH]);
        map[node] = 3;
    }
    grid.sync();

    // ---- P2: markA — dst is a seed (==3) & kept -> atomicMax(src, 2) ----
    // Test ==3 is stable: this phase only writes 2s; seeds stay 3.
    for (int e = tid; e < N_EDGES; e += nthr) {
        if (map[edst[e]] == 3 && edge_veff(e, evals) != 0.0f)
            atomicMax(&map[esrc[e]], 2);
    }
    grid.sync();

    // ---- P3: markB — m(dst)>=2 & kept -> atomicMax(src, 1) ----
    // Test >=2 is stable: this phase only writes 1s.
    for (int e = tid; e < N_EDGES; e += nthr) {
        if (map[edst[e]] >= 2 && edge_veff(e, evals) != 0.0f)
            atomicMax(&map[esrc[e]], 1);
    }
    grid.sync();

    // ---- P4: fused assign: map chunks allocate+pack+zero rows; edge chunks
    // classify and scatter to the class-grouped compact edge list.
    // Concurrent raw/packed map reads handled by level_of(); both correct. ----
    {
        __shared__ int ws[4], w1s[4], sbase[4];
        int t = threadIdx.x, lane = t & 63, w = t >> 6;
        for (int b = blockIdx.x; b < NBLK_M + NBLK_E; b += GRID) {
            __syncthreads();  // protect shared reuse across chunk iterations
            if (b < NBLK_M) {
                int base = b * SCHUNK + t * 16;
                int m[16];
                int s = 0;
#pragma unroll
                for (int j = 0; j < 16; ++j) {
                    int i = base + j;
                    m[j] = (i < N_NODES) ? map[i] : 0;  // raw 0..3 (this block packs it)
                    s += m[j];
                }
                int x = s;
#pragma unroll
                for (int off = 1; off < 64; off <<= 1) {
                    int y = __shfl_up(x, off, 64);
                    if (lane >= off) x += y;
                }
                if (lane == 63) ws[w] = x;
                __syncthreads();
                int woff = 0;
                for (int i = 0; i < w; ++i) woff += ws[i];
                if (t == 0)
                    sbase[0] = atomicAdd(&cnt[C_ROW], ws[0] + ws[1] + ws[2] + ws[3]);
                __syncthreads();
                int run = sbase[0] + woff + (x - s);
                float4 z = {0.f, 0.f, 0.f, 0.f};
#pragma unroll
                for (int j = 0; j < 16; ++j) {
                    if (!m[j]) continue;
                    int i = base + j;
                    int r = run; run += m[j];
                    if (r + m[j] <= POOLROWS) {
                        map[i] = (m[j] << 24) | r;
                        float4* p4 = (float4*)(pool + (size_t)r * DIM);
                        for (int k = 0; k < m[j] * 16; ++k) p4[k] = z;
                    } else {
                        map[i] = 0;  // defensive; never hit at these sizes
                    }
                }
            } else {
                int base = (b - NBLK_M) * SCHUNK + t * 16;
                int lv[16]; float vv[16];
                int s3 = 0, s2 = 0, s1 = 0;
#pragma unroll
                for (int j = 0; j < 16; ++j) {
                    lv[j] = 0; vv[j] = 0.f;
                    int e = base + j;
                    if (e >= N_EDGES) continue;
                    int l = level_of(map[edst[e]]);
                    if (!l) continue;
                    float v = edge_veff(e, evals);
                    if (v == 0.0f) continue;
                    lv[j] = l; vv[j] = v;
                    if (l == 3) s3++; else if (l == 2) s2++; else s1++;
                }
                int p = (s3 << 16) | s2;  // block sums <= 4096/field: no carry
                int x = p, x1 = s1;
#pragma unroll
                for (int off = 1; off < 64; off <<= 1) {
                    int y = __shfl_up(x, off, 64);
                    int y1 = __shfl_up(x1, off, 64);
                    if (lane >= off) { x += y; x1 += y1; }
                }
                if (lane == 63) { ws[w] = x; w1s[w] = x1; }
                __syncthreads();
                int wo = 0, wo1 = 0;
                for (int i = 0; i < w; ++i) { wo += ws[i]; wo1 += w1s[i]; }
                if (t == 0) {
                    int tp = ws[0] + ws[1] + ws[2] + ws[3];
                    int t1 = w1s[0] + w1s[1] + w1s[2] + w1s[3];
                    sbase[1] = atomicAdd(&cnt[C_N3], tp >> 16);
                    sbase[2] = atomicAdd(&cnt[C_N2], tp & 0xFFFF);
                    sbase[3] = atomicAdd(&cnt[C_N1], t1);
                }
                __syncthreads();
                int ex = wo + (x - p);
                int r3 = sbase[1] + (ex >> 16);
                int r2 = sbase[2] + (ex & 0xFFFF);
                int r1 = sbase[3] + wo1 + (x1 - s1);
#pragma unroll
                for (int j = 0; j < 16; ++j) {
                    if (!lv[j]) continue;
                    int e = base + j, pos;
                    if (lv[j] == 3)      pos = 0 * CAPE + (r3++);
                    else if (lv[j] == 2) pos = 1 * CAPE + (r2++);
                    else                 pos = 2 * CAPE + (r1++);
                    el_src[pos] = esrc[e];
                    el_dst[pos] = edst[e];
                    el_v[pos]   = vv[j];
                }
            }
        }
    }
    grid.sync();

    const int n3 = min(cnt[C_N3], CAPE);
    const int n2 = min(cnt[C_N2], CAPE);
    const int n1 = min(cnt[C_N1], CAPE);

    // ---- P5: comp1 — all listed edges: pool[base(d)] += v * raw_input[s] ----
    for (int t = tid; t < (n3 + n2 + n1) * 16; t += nthr) {
        int e = t >> 4, c = (t & 15) << 2;
        int i = (e < n3) ? e
              : (e < n3 + n2) ? (e - n3 + CAPE)
              : (e - n3 - n2 + 2 * CAPE);
        int s = el_src[i];
        int xd = map[el_dst[i]];
        if (xd < (1 << 24)) continue;  // defensive
        int dr = xd & 0xFFFFFF;
        float v = el_v[i];
        const float* srow = (s < N_USER) ? (user_emb + (size_t)s * DIM)
                                         : (item_emb + (size_t)(s - N_USER) * DIM);
        float4 xv = *(const float4*)(srow + c);
        float* drow = pool + (size_t)dr * DIM + c;
        atomicAdd(drow + 0, v * xv.x);
        atomicAdd(drow + 1, v * xv.y);
        atomicAdd(drow + 2, v * xv.z);
        atomicAdd(drow + 3, v * xv.w);
    }
    grid.sync();

    // ---- P6: comp2 — el3+el2: pool[base(d)+1] += v * pool[base(s)] ----
    for (int t = tid; t < (n3 + n2) * 16; t += nthr) {
        int e = t >> 4, c = (t & 15) << 2;
        int i = (e < n3) ? e : (e - n3 + CAPE);
        int xs = map[el_src[i]];
        int xd = map[el_dst[i]];
        if (xs < (1 << 24) || xd < (1 << 24)) continue;  // defensive
        int sr = (xs & 0xFFFFFF);
        int dr = (xd & 0xFFFFFF) + 1;
        float v = el_v[i];
        float4 xv = *(const float4*)(pool + (size_t)sr * DIM + c);
        float* drow = pool + (size_t)dr * DIM + c;
        atomicAdd(drow + 0, v * xv.x);
        atomicAdd(drow + 1, v * xv.y);
        atomicAdd(drow + 2, v * xv.z);
        atomicAdd(drow + 3, v * xv.w);
    }
    grid.sync();

    // ---- P7: comp3 — el3 only: pool[base(d)+2] += v * pool[base(s)+1] ----
    for (int t = tid; t < n3 * 16; t += nthr) {
        int e = t >> 4, c = (t & 15) << 2;
        int xs = map[el_src[e]];
        int xd = map[el_dst[e]];
        if (xs < (1 << 24) || xd < (1 << 24)) continue;  // defensive
        int sr = (xs & 0xFFFFFF) + 1;
        int dr = (xd & 0xFFFFFF) + 2;
        float v = el_v[e];
        float4 xv = *(const float4*)(pool + (size_t)sr * DIM + c);
        float* drow = pool + (size_t)dr * DIM + c;
        atomicAdd(drow + 0, v * xv.x);
        atomicAdd(drow + 1, v * xv.y);
        atomicAdd(drow + 2, v * xv.z);
        atomicAdd(drow + 3, v * xv.w);
    }
    grid.sync();

    // ---- P8: fused extraction + pooling + ratings (one wave per batch b) ----
    {
        int wv = tid >> 6, d = tid & 63;
        for (int b = wv; b < BATCH; b += nthr >> 6) {
            int un = users[b];
            int in_node = N_USER + items[b];
            int ru = map[un] & 0xFFFFFF;
            int ri = map[in_node] & 0xFFFFFF;

            float u0 = user_emb[(size_t)un * DIM + d];
            float i0 = item_emb[(size_t)items[b] * DIM + d];
            float u1 = pool[(size_t)(ru + 0) * DIM + d];
            float u2 = pool[(size_t)(ru + 1) * DIM + d];
            float u3 = pool[(size_t)(ru + 2) * DIM + d];
            float i1 = pool[(size_t)(ri + 0) * DIM + d];
            float i2 = pool[(size_t)(ri + 1) * DIM + d];
            float i3 = pool[(size_t)(ri + 2) * DIM + d];

            size_t base = (size_t)b * 4 * DIM + d;
            inter_layers[base + 0 * DIM] = u0 * i0;
            inter_layers[base + 1 * DIM] = u1 * i1;
            inter_layers[base + 2 * DIM] = u2 * i2;
            inter_layers[base + 3 * DIM] = u3 * i3;

            float lu = (u0 + u1 + u2 + u3) * 0.25f;
            float li = (i0 + i1 + i2 + i3) * 0.25f;
            float p = lu * li;
            inter[(size_t)b * DIM + d] = p;
            float s = p;
#pragma unroll
            for (int off = 32; off > 0; off >>= 1) s += __shfl_down(s, off, 64);
            if (d == 0) ratings[b] = 1.0f / (1.0f + expf(-s));
        }
    }
}

// ---------------------------------------------------------------------------
extern "C" void kernel_launch(void* const* d_in, const int* in_sizes, int n_in,
                              void* d_out, int out_size, void* d_ws, size_t ws_size,
                              hipStream_t stream) {
    const float* user_emb  = (const float*)d_in[0];
    const float* item_emb  = (const float*)d_in[1];
    const float* edge_vals = (const float*)d_in[2];
    const int*   edge_src  = (const int*)d_in[3];
    const int*   edge_dst  = (const int*)d_in[4];
    const int*   users     = (const int*)d_in[5];
    const int*   items     = (const int*)d_in[6];

    float* out          = (float*)d_out;
    float* ratings      = out;                       // [BATCH]
    float* inter        = out + BATCH;               // [BATCH, DIM]
    float* inter_layers = out + BATCH + BATCH * DIM; // [BATCH, 4, DIM]

    char* ws = (char*)d_ws;
    size_t off = 0;
    int* map = (int*)(ws + off); off += (size_t)N_NODES * sizeof(int);
    float* pool = (float*)(ws + off); off += (size_t)POOLROWS * DIM * sizeof(float);
    int* cnt = (int*)(ws + off); off += 256 * sizeof(int);
    int* el_src = (int*)(ws + off); off += (size_t)3 * CAPE * sizeof(int);
    int* el_dst = (int*)(ws + off); off += (size_t)3 * CAPE * sizeof(int);
    float* el_v = (float*)(ws + off); off += (size_t)3 * CAPE * sizeof(float);

    void* kargs[] = {
        (void*)&user_emb, (void*)&item_emb, (void*)&edge_vals,
        (void*)&edge_src, (void*)&edge_dst, (void*)&users, (void*)&items,
        (void*)&map, (void*)&pool, (void*)&cnt,
        (void*)&el_src, (void*)&el_dst, (void*)&el_v,
        (void*)&ratings, (void*)&inter, (void*)&inter_layers,
    };
    hipLaunchCooperativeKernel((const void*)mega_kernel, dim3(GRID), dim3(TPB),
                               kargs, 0, stream);
}

// Round 11
// 164.035 us; speedup vs baseline: 3.7039x; 3.7039x over previous
//
#include <hip/hip_runtime.h>

#define N_USER   300000
#define M_ITEM   700000
#define N_NODES  (N_USER + M_ITEM)
#define DIM      64
#define N_EDGES  1200000
#define BATCH    4096

#define SCHUNK   4096
#define NBLK     ((N_NODES + SCHUNK - 1) / SCHUNK)   // 245 scan blocks

// ---------------------------------------------------------------------------
// Threefry2x32-20, JAX partitionable path (bit-exact, verified round 2).
// ---------------------------------------------------------------------------
__device__ __forceinline__ unsigned rotl32(unsigned x, int r) {
    return (x << r) | (x >> (32 - r));
}

__device__ __forceinline__ float edge_veff(int e, const float* __restrict__ evals) {
    unsigned ks[3] = {0u, 42u, 0u ^ 42u ^ 0x1BD11BDAu};
    unsigned x0 = ks[0];
    unsigned x1 = (unsigned)e + ks[1];
    const int rotA[4] = {13, 15, 26, 6};
    const int rotB[4] = {17, 29, 16, 24};
#pragma unroll
    for (int g = 0; g < 5; ++g) {
#pragma unroll
        for (int j = 0; j < 4; ++j) {
            int r = (g & 1) ? rotB[j] : rotA[j];
            x0 += x1;
            x1 = rotl32(x1, r);
            x1 ^= x0;
        }
        x0 += ks[(g + 1) % 3];
        x1 += ks[(g + 2) % 3] + (unsigned)(g + 1);
    }
    unsigned bits = x0 ^ x1;
    float u = __uint_as_float((bits >> 9) | 0x3F800000u) - 1.0f;
    return (u >= 0.1f) ? evals[e] * (1.0f / 0.9f) : 0.0f;
}

// ---------------------------------------------------------------------------
// P0: zero deg[] and cursor[] (contiguous, 8 MB) — grid-stride int4.
// ---------------------------------------------------------------------------
__global__ void fill_kernel(int4* __restrict__ z4) {
    const int TOT4 = 2 * N_NODES / 4;  // 500,000
    int tid = blockIdx.x * blockDim.x + threadIdx.x;
    int stride = gridDim.x * blockDim.x;
    int4 z = make_int4(0, 0, 0, 0);
    for (int i = tid; i < TOT4; i += stride) z4[i] = z;
}

// ---------------------------------------------------------------------------
// P1: in-degree histogram over dst.
// ---------------------------------------------------------------------------
__global__ void hist_kernel(const int* __restrict__ edst, int* __restrict__ deg) {
    int e = blockIdx.x * blockDim.x + threadIdx.x;
    if (e < N_EDGES) atomicAdd(&deg[edst[e]], 1);
}

// ---------------------------------------------------------------------------
// P2: per-block exclusive prefix of deg -> pre[], block totals -> bs[].
// 245 blocks x 256 threads x 16 elems.
// ---------------------------------------------------------------------------
__global__ void scan1_kernel(const int* __restrict__ deg, int* __restrict__ pre,
                             int* __restrict__ bs) {
    int b = blockIdx.x, t = threadIdx.x;
    int lane = t & 63, w = t >> 6;
    int base = b * SCHUNK + t * 16;
    int v[16];
    int s = 0;
#pragma unroll
    for (int j = 0; j < 16; ++j) {
        int i = base + j;
        v[j] = (i < N_NODES) ? deg[i] : 0;
        s += v[j];
    }
    int x = s;
#pragma unroll
    for (int off = 1; off < 64; off <<= 1) {
        int y = __shfl_up(x, off, 64);
        if (lane >= off) x += y;
    }
    __shared__ int ws[4];
    if (lane == 63) ws[w] = x;
    __syncthreads();
    int woff = 0;
    for (int i = 0; i < w; ++i) woff += ws[i];
    int run = woff + (x - s);
#pragma unroll
    for (int j = 0; j < 16; ++j) {
        int i = base + j;
        if (i < N_NODES) pre[i] = run;
        run += v[j];
    }
    if (t == 255) bs[b] = ws[0] + ws[1] + ws[2] + ws[3];
}

// ---------------------------------------------------------------------------
// P3: single-block exclusive scan of the 245 block totals.
// ---------------------------------------------------------------------------
__global__ void scan2_kernel(int* __restrict__ bs) {
    __shared__ int sm[256];
    int t = threadIdx.x;
    int v = (t < NBLK) ? bs[t] : 0;
    sm[t] = v;
    __syncthreads();
    for (int off = 1; off < 256; off <<= 1) {
        int y = (t >= off) ? sm[t - off] : 0;
        __syncthreads();
        sm[t] += y;
        __syncthreads();
    }
    if (t < NBLK) bs[t] = sm[t] - v;  // exclusive
}

// ---------------------------------------------------------------------------
// P4: scatter edges into CSR slots (threefry veff computed once, stored).
// Slot within a row via atomicAdd on cursor (per-node, contention <= deg~12).
// ---------------------------------------------------------------------------
__global__ void scatter_kernel(const int* __restrict__ esrc,
                               const int* __restrict__ edst,
                               const float* __restrict__ evals,
                               const int* __restrict__ pre,
                               const int* __restrict__ bs,
                               int* __restrict__ cursor,
                               int* __restrict__ csr_src,
                               float* __restrict__ csr_val) {
    int e = blockIdx.x * blockDim.x + threadIdx.x;
    if (e >= N_EDGES) return;
    int d = edst[e];
    int rowstart = pre[d] + bs[d >> 12];        // SCHUNK = 4096
    int pos = rowstart + atomicAdd(&cursor[d], 1);
    csr_src[pos] = esrc[e];
    csr_val[pos] = edge_veff(e, evals);
}

// ---------------------------------------------------------------------------
// P5: fused recursive pull + outputs. One wave per batch element b; lane = dim.
// All loop bounds wave-uniform (node-indexed) -> zero divergence; every u0
// gather is a coalesced 256B row read. Recomputation of shared subtrees is
// cheap (avg deg 1.2 -> ~4.4 leaf gathers per node per level-3 pull).
// ---------------------------------------------------------------------------
__device__ __forceinline__ float emb0(const float* __restrict__ ue,
                                      const float* __restrict__ ie, int s, int d) {
    return (s < N_USER) ? ue[(size_t)s * DIM + d] : ie[(size_t)(s - N_USER) * DIM + d];
}

__device__ __forceinline__ void pull3(int n, int d,
                                      const float* __restrict__ ue,
                                      const float* __restrict__ ie,
                                      const int* __restrict__ pre,
                                      const int* __restrict__ bs,
                                      const int* __restrict__ degc,
                                      const int* __restrict__ csr_src,
                                      const float* __restrict__ csr_val,
                                      float& u1, float& u2, float& u3) {
    u1 = 0.f; u2 = 0.f; u3 = 0.f;
    int r0 = pre[n] + bs[n >> 12];
    int l0 = degc[n];
    for (int e1 = r0; e1 < r0 + l0; ++e1) {
        float v1 = csr_val[e1];
        if (v1 == 0.f) continue;
        int s1 = csr_src[e1];
        u1 += v1 * emb0(ue, ie, s1, d);
        int r1 = pre[s1] + bs[s1 >> 12];
        int l1 = degc[s1];
        float u1s1 = 0.f, u2s1 = 0.f;
        for (int e2 = r1; e2 < r1 + l1; ++e2) {
            float v2 = csr_val[e2];
            if (v2 == 0.f) continue;
            int s2 = csr_src[e2];
            u1s1 += v2 * emb0(ue, ie, s2, d);
            int r2 = pre[s2] + bs[s2 >> 12];
            int l2 = degc[s2];
            float u1s2 = 0.f;
            for (int e3 = r2; e3 < r2 + l2; ++e3) {
                float v3 = csr_val[e3];
                if (v3 == 0.f) continue;
                u1s2 += v3 * emb0(ue, ie, csr_src[e3], d);
            }
            u2s1 += v2 * u1s2;
        }
        u2 += v1 * u1s1;
        u3 += v1 * u2s1;
    }
}

__global__ void out_kernel(const float* __restrict__ user_emb,
                           const float* __restrict__ item_emb,
                           const int* __restrict__ users,
                           const int* __restrict__ items,
                           const int* __restrict__ pre,
                           const int* __restrict__ bs,
                           const int* __restrict__ degc,   // cursor == deg
                           const int* __restrict__ csr_src,
                           const float* __restrict__ csr_val,
                           float* __restrict__ ratings,
                           float* __restrict__ inter,
                           float* __restrict__ inter_layers) {
    int gt = blockIdx.x * blockDim.x + threadIdx.x;
    int b = gt >> 6, d = gt & 63;
    if (b >= BATCH) return;
    int un = users[b];
    int in_node = N_USER + items[b];

    float u0 = user_emb[(size_t)un * DIM + d];
    float i0 = item_emb[(size_t)items[b] * DIM + d];
    float u1, u2, u3, i1, i2, i3;
    pull3(un, d, user_emb, item_emb, pre, bs, degc, csr_src, csr_val, u1, u2, u3);
    pull3(in_node, d, user_emb, item_emb, pre, bs, degc, csr_src, csr_val, i1, i2, i3);

    size_t base = (size_t)b * 4 * DIM + d;
    inter_layers[base + 0 * DIM] = u0 * i0;
    inter_layers[base + 1 * DIM] = u1 * i1;
    inter_layers[base + 2 * DIM] = u2 * i2;
    inter_layers[base + 3 * DIM] = u3 * i3;

    float lu = (u0 + u1 + u2 + u3) * 0.25f;
    float li = (i0 + i1 + i2 + i3) * 0.25f;
    float p = lu * li;
    inter[(size_t)b * DIM + d] = p;
    float s = p;
#pragma unroll
    for (int off = 32; off > 0; off >>= 1) s += __shfl_down(s, off, 64);
    if (d == 0) ratings[b] = 1.0f / (1.0f + expf(-s));
}

// ---------------------------------------------------------------------------
extern "C" void kernel_launch(void* const* d_in, const int* in_sizes, int n_in,
                              void* d_out, int out_size, void* d_ws, size_t ws_size,
                              hipStream_t stream) {
    const float* user_emb  = (const float*)d_in[0];
    const float* item_emb  = (const float*)d_in[1];
    const float* edge_vals = (const float*)d_in[2];
    const int*   edge_src  = (const int*)d_in[3];
    const int*   edge_dst  = (const int*)d_in[4];
    const int*   users     = (const int*)d_in[5];
    const int*   items     = (const int*)d_in[6];

    float* out          = (float*)d_out;
    float* ratings      = out;                       // [BATCH]
    float* inter        = out + BATCH;               // [BATCH, DIM]
    float* inter_layers = out + BATCH + BATCH * DIM; // [BATCH, 4, DIM]

    char* ws = (char*)d_ws;
    size_t off = 0;
    int* deg     = (int*)(ws + off); off += (size_t)N_NODES * sizeof(int);
    int* cursor  = (int*)(ws + off); off += (size_t)N_NODES * sizeof(int);
    int* pre     = (int*)(ws + off); off += (size_t)N_NODES * sizeof(int);
    int* bs      = (int*)(ws + off); off += 1024 * sizeof(int);
    int* csr_src = (int*)(ws + off); off += (size_t)N_EDGES * sizeof(int);
    float* csr_val = (float*)(ws + off); off += (size_t)N_EDGES * sizeof(float);

    const dim3 blk(256);
    const dim3 egrid((N_EDGES + 255) / 256);

    fill_kernel<<<512, blk, 0, stream>>>((int4*)deg);  // deg+cursor contiguous
    hist_kernel<<<egrid, blk, 0, stream>>>(edge_dst, deg);
    scan1_kernel<<<NBLK, blk, 0, stream>>>(deg, pre, bs);
    scan2_kernel<<<1, 256, 0, stream>>>(bs);
    scatter_kernel<<<egrid, blk, 0, stream>>>(edge_src, edge_dst, edge_vals,
                                              pre, bs, cursor, csr_src, csr_val);
    out_kernel<<<(BATCH * 64 + 255) / 256, blk, 0, stream>>>(
        user_emb, item_emb, users, items, pre, bs, cursor, csr_src, csr_val,
        ratings, inter, inter_layers);
}

// Round 12
// 82.887 us; speedup vs baseline: 7.3301x; 1.9790x over previous
//
#include <hip/hip_runtime.h>

#define N_USER   300000
#define M_ITEM   700000
#define N_NODES  (N_USER + M_ITEM)
#define DIM      64
#define N_EDGES  1200000
#define BATCH    4096

// ---------------------------------------------------------------------------
// Threefry2x32-20, JAX partitionable path (bit-exact, verified round 2).
// ---------------------------------------------------------------------------
__device__ __forceinline__ unsigned rotl32(unsigned x, int r) {
    return (x << r) | (x >> (32 - r));
}

__device__ __forceinline__ float edge_veff(int e, float val) {
    unsigned ks[3] = {0u, 42u, 0u ^ 42u ^ 0x1BD11BDAu};
    unsigned x0 = ks[0];
    unsigned x1 = (unsigned)e + ks[1];
    const int rotA[4] = {13, 15, 26, 6};
    const int rotB[4] = {17, 29, 16, 24};
#pragma unroll
    for (int g = 0; g < 5; ++g) {
#pragma unroll
        for (int j = 0; j < 4; ++j) {
            int r = (g & 1) ? rotB[j] : rotA[j];
            x0 += x1;
            x1 = rotl32(x1, r);
            x1 ^= x0;
        }
        x0 += ks[(g + 1) % 3];
        x1 += ks[(g + 2) % 3] + (unsigned)(g + 1);
    }
    unsigned bits = x0 ^ x1;
    float u = __uint_as_float((bits >> 9) | 0x3F800000u) - 1.0f;
    return (u >= 0.1f) ? val * (1.0f / 0.9f) : 0.0f;
}

// ---------------------------------------------------------------------------
// P0: head[n] = -1 (grid-stride int4).
// ---------------------------------------------------------------------------
__global__ void fill_kernel(int4* __restrict__ head4) {
    const int TOT4 = N_NODES / 4;  // 250,000
    int tid = blockIdx.x * blockDim.x + threadIdx.x;
    int stride = gridDim.x * blockDim.x;
    int4 m1 = make_int4(-1, -1, -1, -1);
    for (int i = tid; i < TOT4; i += stride) head4[i] = m1;
}

// ---------------------------------------------------------------------------
// P1: push kept edges into per-dst linked lists. Edge index = storage slot:
//   nxt[e] = atomicExch(&head[dst], e); val[e] = veff.
// Dropped edges (10%) are skipped entirely. Contention per head ~ in-deg 1.2.
// ---------------------------------------------------------------------------
__global__ void push_kernel(const int* __restrict__ edst,
                            const float* __restrict__ evals,
                            int* __restrict__ head,
                            int* __restrict__ nxt,
                            float* __restrict__ val) {
    int e = blockIdx.x * blockDim.x + threadIdx.x;
    if (e >= N_EDGES) return;
    float v = edge_veff(e, evals[e]);
    if (v == 0.0f) return;
    val[e] = v;
    nxt[e] = atomicExch(&head[edst[e]], e);
}

// ---------------------------------------------------------------------------
// P2: fused recursive pull + all outputs. One wave per batch element; lane =
// dim. List pointers (head/nxt/val/esrc) are wave-uniform broadcast loads;
// embedding rows are 256B coalesced gathers. Expected hops per root:
// deg + deg^2 + deg^3 ~ 4.4 (deg ~ 1.2).
// ---------------------------------------------------------------------------
__device__ __forceinline__ float emb0(const float* __restrict__ ue,
                                      const float* __restrict__ ie, int s, int d) {
    return (s < N_USER) ? ue[(size_t)s * DIM + d] : ie[(size_t)(s - N_USER) * DIM + d];
}

__device__ __forceinline__ void pull3(int n, int d,
                                      const float* __restrict__ ue,
                                      const float* __restrict__ ie,
                                      const int* __restrict__ head,
                                      const int* __restrict__ nxt,
                                      const float* __restrict__ val,
                                      const int* __restrict__ esrc,
                                      float& u1, float& u2, float& u3) {
    u1 = 0.f; u2 = 0.f; u3 = 0.f;
    for (int e1 = head[n]; e1 != -1; e1 = nxt[e1]) {
        float v1 = val[e1];
        int s1 = esrc[e1];
        u1 += v1 * emb0(ue, ie, s1, d);
        float a1 = 0.f, a2 = 0.f;
        for (int e2 = head[s1]; e2 != -1; e2 = nxt[e2]) {
            float v2 = val[e2];
            int s2 = esrc[e2];
            a1 += v2 * emb0(ue, ie, s2, d);
            float b1 = 0.f;
            for (int e3 = head[s2]; e3 != -1; e3 = nxt[e3]) {
                b1 += val[e3] * emb0(ue, ie, esrc[e3], d);
            }
            a2 += v2 * b1;
        }
        u2 += v1 * a1;
        u3 += v1 * a2;
    }
}

__global__ void out_kernel(const float* __restrict__ user_emb,
                           const float* __restrict__ item_emb,
                           const int* __restrict__ users,
                           const int* __restrict__ items,
                           const int* __restrict__ head,
                           const int* __restrict__ nxt,
                           const float* __restrict__ val,
                           const int* __restrict__ esrc,
                           float* __restrict__ ratings,
                           float* __restrict__ inter,
                           float* __restrict__ inter_layers) {
    int gt = blockIdx.x * blockDim.x + threadIdx.x;
    int b = gt >> 6, d = gt & 63;
    if (b >= BATCH) return;
    int un = users[b];
    int in_node = N_USER + items[b];

    float u0 = user_emb[(size_t)un * DIM + d];
    float i0 = item_emb[(size_t)items[b] * DIM + d];
    float u1, u2, u3, i1, i2, i3;
    pull3(un, d, user_emb, item_emb, head, nxt, val, esrc, u1, u2, u3);
    pull3(in_node, d, user_emb, item_emb, head, nxt, val, esrc, i1, i2, i3);

    size_t base = (size_t)b * 4 * DIM + d;
    inter_layers[base + 0 * DIM] = u0 * i0;
    inter_layers[base + 1 * DIM] = u1 * i1;
    inter_layers[base + 2 * DIM] = u2 * i2;
    inter_layers[base + 3 * DIM] = u3 * i3;

    float lu = (u0 + u1 + u2 + u3) * 0.25f;
    float li = (i0 + i1 + i2 + i3) * 0.25f;
    float p = lu * li;
    inter[(size_t)b * DIM + d] = p;
    float s = p;
#pragma unroll
    for (int off = 32; off > 0; off >>= 1) s += __shfl_down(s, off, 64);
    if (d == 0) ratings[b] = 1.0f / (1.0f + expf(-s));
}

// ---------------------------------------------------------------------------
extern "C" void kernel_launch(void* const* d_in, const int* in_sizes, int n_in,
                              void* d_out, int out_size, void* d_ws, size_t ws_size,
                              hipStream_t stream) {
    const float* user_emb  = (const float*)d_in[0];
    const float* item_emb  = (const float*)d_in[1];
    const float* edge_vals = (const float*)d_in[2];
    const int*   edge_src  = (const int*)d_in[3];
    const int*   edge_dst  = (const int*)d_in[4];
    const int*   users     = (const int*)d_in[5];
    const int*   items     = (const int*)d_in[6];

    float* out          = (float*)d_out;
    float* ratings      = out;                       // [BATCH]
    float* inter        = out + BATCH;               // [BATCH, DIM]
    float* inter_layers = out + BATCH + BATCH * DIM; // [BATCH, 4, DIM]

    char* ws = (char*)d_ws;
    size_t off = 0;
    int* head = (int*)(ws + off); off += (size_t)N_NODES * sizeof(int);
    int* nxt  = (int*)(ws + off); off += (size_t)N_EDGES * sizeof(int);
    float* val = (float*)(ws + off); off += (size_t)N_EDGES * sizeof(float);

    const dim3 blk(256);

    fill_kernel<<<512, blk, 0, stream>>>((int4*)head);
    push_kernel<<<(N_EDGES + 255) / 256, blk, 0, stream>>>(
        edge_dst, edge_vals, head, nxt, val);
    out_kernel<<<(BATCH * 64 + 255) / 256, blk, 0, stream>>>(
        user_emb, item_emb, users, items, head, nxt, val, edge_src,
        ratings, inter, inter_layers);
}

// Round 13
// 79.756 us; speedup vs baseline: 7.6178x; 1.0393x over previous
//
#include <hip/hip_runtime.h>

#define N_USER   300000
#define M_ITEM   700000
#define N_NODES  (N_USER + M_ITEM)
#define DIM      64
#define N_EDGES  1200000
#define BATCH    4096

// ---------------------------------------------------------------------------
// Threefry2x32-20, JAX partitionable path (bit-exact, verified round 2).
// ---------------------------------------------------------------------------
__device__ __forceinline__ unsigned rotl32(unsigned x, int r) {
    return (x << r) | (x >> (32 - r));
}

__device__ __forceinline__ float edge_veff(int e, float val) {
    unsigned ks[3] = {0u, 42u, 0u ^ 42u ^ 0x1BD11BDAu};
    unsigned x0 = ks[0];
    unsigned x1 = (unsigned)e + ks[1];
    const int rotA[4] = {13, 15, 26, 6};
    const int rotB[4] = {17, 29, 16, 24};
#pragma unroll
    for (int g = 0; g < 5; ++g) {
#pragma unroll
        for (int j = 0; j < 4; ++j) {
            int r = (g & 1) ? rotB[j] : rotA[j];
            x0 += x1;
            x1 = rotl32(x1, r);
            x1 ^= x0;
        }
        x0 += ks[(g + 1) % 3];
        x1 += ks[(g + 2) % 3] + (unsigned)(g + 1);
    }
    unsigned bits = x0 ^ x1;
    float u = __uint_as_float((bits >> 9) | 0x3F800000u) - 1.0f;
    return (u >= 0.1f) ? val * (1.0f / 0.9f) : 0.0f;
}

// ---------------------------------------------------------------------------
// P0: head[n] = -1 (grid-stride int4).
// ---------------------------------------------------------------------------
__global__ void fill_kernel(int4* __restrict__ head4) {
    const int TOT4 = N_NODES / 4;  // 250,000
    int tid = blockIdx.x * blockDim.x + threadIdx.x;
    int stride = gridDim.x * blockDim.x;
    int4 m1 = make_int4(-1, -1, -1, -1);
    for (int i = tid; i < TOT4; i += stride) head4[i] = m1;
}

// ---------------------------------------------------------------------------
// P1: push kept edges into per-dst linked lists, AoS node = {nxt, src, val}.
// One 16B coalesced store per kept edge; node[e] only read after the kernel
// boundary, so the exch-then-store order is race-free.
// ---------------------------------------------------------------------------
__global__ void push_kernel(const int* __restrict__ esrc,
                            const int* __restrict__ edst,
                            const float* __restrict__ evals,
                            int* __restrict__ head,
                            int4* __restrict__ node) {
    int e = blockIdx.x * blockDim.x + threadIdx.x;
    if (e >= N_EDGES) return;
    float v = edge_veff(e, evals[e]);
    if (v == 0.0f) return;
    int old = atomicExch(&head[edst[e]], e);
    node[e] = make_int4(old, esrc[e], __float_as_int(v), 0);
}

// ---------------------------------------------------------------------------
// P2: one WAVE PER ROOT (user and item separately -> 2x chase parallelism),
// one int4 load per list hop. Partials exchanged via LDS inside a 4-wave
// block; even waves write the outputs for their batch element.
// ---------------------------------------------------------------------------
__device__ __forceinline__ float emb0(const float* __restrict__ ue,
                                      const float* __restrict__ ie, int s, int d) {
    return (s < N_USER) ? ue[(size_t)s * DIM + d] : ie[(size_t)(s - N_USER) * DIM + d];
}

__device__ __forceinline__ void pull3(int n, int d,
                                      const float* __restrict__ ue,
                                      const float* __restrict__ ie,
                                      const int* __restrict__ head,
                                      const int4* __restrict__ node,
                                      float& u1, float& u2, float& u3) {
    u1 = 0.f; u2 = 0.f; u3 = 0.f;
    for (int e1 = head[n]; e1 != -1; ) {
        int4 n1 = node[e1];
        e1 = n1.x;
        int s1 = n1.y;
        float v1 = __int_as_float(n1.z);
        u1 += v1 * emb0(ue, ie, s1, d);
        float a1 = 0.f, a2 = 0.f;
        for (int e2 = head[s1]; e2 != -1; ) {
            int4 n2 = node[e2];
            e2 = n2.x;
            int s2 = n2.y;
            float v2 = __int_as_float(n2.z);
            a1 += v2 * emb0(ue, ie, s2, d);
            float b1 = 0.f;
            for (int e3 = head[s2]; e3 != -1; ) {
                int4 n3 = node[e3];
                e3 = n3.x;
                b1 += __int_as_float(n3.z) * emb0(ue, ie, n3.y, d);
            }
            a2 += v2 * b1;
        }
        u2 += v1 * a1;
        u3 += v1 * a2;
    }
}

__global__ void out_kernel(const float* __restrict__ user_emb,
                           const float* __restrict__ item_emb,
                           const int* __restrict__ users,
                           const int* __restrict__ items,
                           const int* __restrict__ head,
                           const int4* __restrict__ node,
                           float* __restrict__ ratings,
                           float* __restrict__ inter,
                           float* __restrict__ inter_layers) {
    __shared__ float sh[4][4][DIM];  // [wave][layer][dim]
    int w = threadIdx.x >> 6;        // wave in block: 0..3
    int d = threadIdx.x & 63;
    int b = blockIdx.x * 2 + (w >> 1);        // batch element
    bool is_item = (w & 1);

    int root = is_item ? (N_USER + items[b]) : users[b];
    float x0 = emb0(user_emb, item_emb, root, d);
    float x1, x2, x3;
    pull3(root, d, user_emb, item_emb, head, node, x1, x2, x3);

    sh[w][0][d] = x0;
    sh[w][1][d] = x1;
    sh[w][2][d] = x2;
    sh[w][3][d] = x3;
    __syncthreads();

    if (!is_item) {  // even waves write outputs for their b
        float i0 = sh[w + 1][0][d];
        float i1 = sh[w + 1][1][d];
        float i2 = sh[w + 1][2][d];
        float i3 = sh[w + 1][3][d];

        size_t base = (size_t)b * 4 * DIM + d;
        inter_layers[base + 0 * DIM] = x0 * i0;
        inter_layers[base + 1 * DIM] = x1 * i1;
        inter_layers[base + 2 * DIM] = x2 * i2;
        inter_layers[base + 3 * DIM] = x3 * i3;

        float lu = (x0 + x1 + x2 + x3) * 0.25f;
        float li = (i0 + i1 + i2 + i3) * 0.25f;
        float p = lu * li;
        inter[(size_t)b * DIM + d] = p;
        float s = p;
#pragma unroll
        for (int off = 32; off > 0; off >>= 1) s += __shfl_down(s, off, 64);
        if (d == 0) ratings[b] = 1.0f / (1.0f + expf(-s));
    }
}

// ---------------------------------------------------------------------------
extern "C" void kernel_launch(void* const* d_in, const int* in_sizes, int n_in,
                              void* d_out, int out_size, void* d_ws, size_t ws_size,
                              hipStream_t stream) {
    const float* user_emb  = (const float*)d_in[0];
    const float* item_emb  = (const float*)d_in[1];
    const float* edge_vals = (const float*)d_in[2];
    const int*   edge_src  = (const int*)d_in[3];
    const int*   edge_dst  = (const int*)d_in[4];
    const int*   users     = (const int*)d_in[5];
    const int*   items     = (const int*)d_in[6];

    float* out          = (float*)d_out;
    float* ratings      = out;                       // [BATCH]
    float* inter        = out + BATCH;               // [BATCH, DIM]
    float* inter_layers = out + BATCH + BATCH * DIM; // [BATCH, 4, DIM]

    char* ws = (char*)d_ws;
    size_t off = 0;
    int* head = (int*)(ws + off); off += (size_t)N_NODES * sizeof(int);
    int4* node = (int4*)(ws + off); off += (size_t)N_EDGES * sizeof(int4);

    const dim3 blk(256);

    fill_kernel<<<512, blk, 0, stream>>>((int4*)head);
    push_kernel<<<(N_EDGES + 255) / 256, blk, 0, stream>>>(
        edge_src, edge_dst, edge_vals, head, (int4*)node);
    out_kernel<<<BATCH / 2, blk, 0, stream>>>(
        user_emb, item_emb, users, items, head, node,
        ratings, inter, inter_layers);
}